// Round 1
// 209.295 us; speedup vs baseline: 1.0187x; 1.0187x over previous
//
#include <hip/hip_runtime.h>

// Problem constants (fixed by the reference)
#define BATCH 256
#define CDIM  2048
#define HW    49
#define KDIM  16

#define NT     512            // threads per block (8 waves)
#define TILE   128            // c's per phase-1 tile
#define NTILE  (CDIM/TILE)    // 16
#define RED_H  37             // per-h4 stride in reduction scratch (odd*, spreads banks)
#define RED_CS (16*RED_H)     // 592 floats per c-slice
#define CHUNK2 512            // c rows per phase-2 chunk

// One block per batch image. grid = 256 = CU count -> 1 block/CU.
// Phase 1: P[k][hw] = sum_c w[k][c]*fm[c][hw]      (tiled over c, LDS, reg-prefetch)
// Reduce:  32 c-slices -> P, apply BN + 1/49 -> Pt[hw][k] in LDS
// Phase 2: out[b][k][c] = sum_hw Pt[hw][k]*fm[c][hw]  (fm restaged per 512-row chunk)
__global__ __launch_bounds__(NT) void fused_kernel(
    const float* __restrict__ fm, const float* __restrict__ w16,
    const float* __restrict__ gamma, const float* __restrict__ beta,
    const float* __restrict__ mean, const float* __restrict__ var,
    float* __restrict__ out)
{
    // big: reduction scratch (18944 floats) then phase-2 fm rows (25088 floats)
    __shared__ __align__(16) float big[CHUNK2 * HW];       // 100352 B
    __shared__ __align__(16) float fmt[TILE * HW + 32];    // phase-1 fm tile, linear rows of 49
    __shared__ __align__(16) float wt[TILE * KDIM];        // wt[cc][k], current tile's weights
    __shared__ __align__(16) float Pt[HW * KDIM];          // Pt[hw][k], BN'd, /49 folded
    // total LDS = 136,896 B (<160 KiB; 1 block/CU)

    const int tid = threadIdx.x;
    const int b   = blockIdx.x;
    const float* __restrict__ fmb = fm + (size_t)b * CDIM * HW;

    const int h4 = tid & 15;   // hw quad: hw = 4*h4+e  (h4>=13 is dead work, discarded)
    const int cs = tid >> 4;   // 0..31 c-slice (c mod 32 == cs)

    float acc[KDIM][4];
    #pragma unroll
    for (int k = 0; k < KDIM; ++k) {
        acc[k][0] = 0.f; acc[k][1] = 0.f; acc[k][2] = 0.f; acc[k][3] = 0.f;
    }

    // ---- prologue: stage tile 0 (fm linear copy; w transposed, linear LDS write) ----
    for (int i = tid; i < TILE * KDIM; i += NT) {           // wt[cl*16+kk] = w16[kk][cl]
        const int kk = i & 15, cl = i >> 4;
        wt[i] = w16[kk * CDIM + cl];
    }
    {
        const float4* src = (const float4*)fmb;
        float4* dst = (float4*)fmt;
        for (int i = tid; i < (TILE * HW) / 4; i += NT) dst[i] = src[i];
    }

    const bool has4 = (tid < (TILE * HW) / 4 - 3 * NT);     // tid < 32: 4th fm prefetch slot

    // ================= phase 1: tiles over C =================
    for (int t = 0; t < NTILE; ++t) {
        __syncthreads();   // staged fmt/wt visible

        // register-prefetch next tile (global latency hides under compute)
        float4 pf0, pf1, pf2, pf3;
        float  wp0, wp1, wp2, wp3;
        if (t < NTILE - 1) {
            const float4* nsrc = (const float4*)(fmb + (t + 1) * TILE * HW);
            pf0 = nsrc[tid]; pf1 = nsrc[tid + NT]; pf2 = nsrc[tid + 2 * NT];
            if (has4) pf3 = nsrc[tid + 3 * NT];
            const int nct = (t + 1) * TILE;
            {
                int i = tid;          wp0 = w16[(i & 15) * CDIM + nct + (i >> 4)];
                i = tid + NT;         wp1 = w16[(i & 15) * CDIM + nct + (i >> 4)];
                i = tid + 2 * NT;     wp2 = w16[(i & 15) * CDIM + nct + (i >> 4)];
                i = tid + 3 * NT;     wp3 = w16[(i & 15) * CDIM + nct + (i >> 4)];
            }
        }

        // compute: 4 cc per thread; rows of 49 (odd stride) + cc=cs+32j -> <=2-way banks (free)
        #pragma unroll
        for (int j = 0; j < TILE / 32; ++j) {
            const int cc = cs + 32 * j;
            const float* fr = fmt + cc * HW + 4 * h4;
            const float f0 = fr[0], f1 = fr[1], f2 = fr[2], f3 = fr[3];
            const float4* wq = (const float4*)(wt + cc * KDIM);
            float wv[16];
            *(float4*)&wv[0]  = wq[0];
            *(float4*)&wv[4]  = wq[1];
            *(float4*)&wv[8]  = wq[2];
            *(float4*)&wv[12] = wq[3];
            #pragma unroll
            for (int k = 0; k < KDIM; ++k) {
                acc[k][0] += wv[k] * f0;
                acc[k][1] += wv[k] * f1;
                acc[k][2] += wv[k] * f2;
                acc[k][3] += wv[k] * f3;
            }
        }

        __syncthreads();   // all reads of fmt/wt done
        if (t < NTILE - 1) {
            float4* dst = (float4*)fmt;
            dst[tid] = pf0; dst[tid + NT] = pf1; dst[tid + 2 * NT] = pf2;
            if (has4) dst[tid + 3 * NT] = pf3;
            wt[tid] = wp0; wt[tid + NT] = wp1; wt[tid + 2 * NT] = wp2; wt[tid + 3 * NT] = wp3;
        }
    }

    // ====== reduce 32 c-slices + BN -> Pt[hw][k] (2 rounds of 8 k's) ======
    {
        float* red = big;                      // 32*592 = 18944 floats
        const int kw  = tid >> 6;              // wave id = k within group (0..7)
        const int hw2 = tid & 63;
        const int rb  = (hw2 >> 2) * RED_H + kw * 4 + (hw2 & 3);
        #pragma unroll
        for (int r = 0; r < 2; ++r) {
            __syncthreads();                   // (r=1: previous round's reads done)
            #pragma unroll
            for (int kk = 0; kk < 8; ++kk) {
                #pragma unroll
                for (int e = 0; e < 4; ++e)
                    red[cs * RED_CS + h4 * RED_H + kk * 4 + e] = acc[r * 8 + kk][e];
            }
            __syncthreads();
            if (hw2 < HW) {
                float s = 0.f;
                #pragma unroll
                for (int c = 0; c < 32; ++c) s += red[c * RED_CS + rb];
                const int k = r * 8 + kw;
                const float inv   = gamma[k] * rsqrtf(var[k] + 1e-5f);
                const float shift = beta[k] - mean[k] * inv;
                Pt[hw2 * KDIM + k] = (s * inv + shift) * (1.0f / 49.0f);
            }
        }
    }

    // ================= phase 2: out[b][k][c] =================
    for (int ch = 0; ch < CDIM / CHUNK2; ++ch) {
        __syncthreads();                       // red/Pt reads done; big free
        {
            const float4* src = (const float4*)(fmb + ch * CHUNK2 * HW);
            float4* dst = (float4*)big;
            for (int i = tid; i < (CHUNK2 * HW) / 4; i += NT) dst[i] = src[i];
        }
        __syncthreads();

        float a[KDIM];
        #pragma unroll
        for (int k = 0; k < KDIM; ++k) a[k] = 0.f;

        const float* row = big + tid * HW;     // stride 49 (odd) -> 2-way banks, free
        #pragma unroll 7
        for (int hw = 0; hw < HW; ++hw) {
            const float f = row[hw];
            const float4* pv = (const float4*)(Pt + hw * KDIM);  // wave-broadcast reads
            const float4 p0 = pv[0], p1 = pv[1], p2 = pv[2], p3 = pv[3];
            a[0]  += p0.x * f; a[1]  += p0.y * f; a[2]  += p0.z * f; a[3]  += p0.w * f;
            a[4]  += p1.x * f; a[5]  += p1.y * f; a[6]  += p1.z * f; a[7]  += p1.w * f;
            a[8]  += p2.x * f; a[9]  += p2.y * f; a[10] += p2.z * f; a[11] += p2.w * f;
            a[12] += p3.x * f; a[13] += p3.y * f; a[14] += p3.z * f; a[15] += p3.w * f;
        }

        float* ob = out + (size_t)b * (KDIM * CDIM) + ch * CHUNK2 + tid;
        #pragma unroll
        for (int k = 0; k < KDIM; ++k) ob[k * CDIM] = a[k];
    }
}

extern "C" void kernel_launch(void* const* d_in, const int* in_sizes, int n_in,
                              void* d_out, int out_size, void* d_ws, size_t ws_size,
                              hipStream_t stream) {
    const float* fm    = (const float*)d_in[0];
    const float* w16   = (const float*)d_in[1];
    const float* gamma = (const float*)d_in[2];
    const float* beta  = (const float*)d_in[3];
    const float* mean  = (const float*)d_in[4];
    const float* var   = (const float*)d_in[5];
    float* out = (float*)d_out;
    (void)d_ws; (void)ws_size;

    fused_kernel<<<BATCH, NT, 0, stream>>>(fm, w16, gamma, beta, mean, var, out);
}